// Round 6
// baseline (8339.801 us; speedup 1.0000x reference)
//
#include <hip/hip_runtime.h>
#include <hip/hip_bf16.h>

// HierESN (fp32 I/O): out[t] = [v1(t)|v2(t)], v' = .5v + .5tanh(v@W + u@Win)
// A: U = X @ Win1 (bf16 MFMA)      B: persistent coop scan layer1 (custom barrier)
// C: U = V1bf @ Win2 (bf16 MFMA)   D: persistent coop scan layer2
// Scan: 250 blocks x 512 thr, 16 cols/block. Packed sparse W per block as
// [slotgroup][col][4slots] -> uint4 gather loads (1KB/wave), L2-resident.
// Cross-step v via sc0sc1-bypass loads/stores (L3 coherence point); custom
// monotone-counter barrier, counters on separate 64B lines; out/vhist writes
// pushed off the critical path (drain during next poll).

typedef __bf16 bf16;
typedef __bf16 bf16x8 __attribute__((ext_vector_type(8)));
typedef float  f32x4  __attribute__((ext_vector_type(4)));
typedef unsigned uint4v __attribute__((ext_vector_type(4)));

#define RDIM 4000
#define TSTEPS 1000
#define CAP 640            // slots per column (binomial(4000,0.1) max ~475)
#define NBLK 250           // scan blocks
#define CB 16              // cols per block
#define CH 8               // compress row-chunks (500 rows each)

__device__ inline unsigned pack_rne(float w, unsigned row) {
    unsigned u = __float_as_uint(w);
    return ((u + 0x7FFFu + ((u >> 16) & 1u)) & 0xFFFF0000u) | row;
}

// two 16B cache-bypassing loads, both in flight, single drain
__device__ inline void stage2(const float* p0, const float* p1,
                              f32x4& a, f32x4& b) {
    asm volatile(
        "global_load_dwordx4 %0, %2, off sc0 sc1\n\t"
        "global_load_dwordx4 %1, %3, off sc0 sc1\n\t"
        "s_waitcnt vmcnt(0)"
        : "=&v"(a), "=&v"(b)
        : "v"(p0), "v"(p1)
        : "memory");
}

// ---- compress pass 1: nnz count per (chunk, col) ----
__global__ __launch_bounds__(256) void count_k(const float* __restrict__ W,
                                               unsigned* __restrict__ cnts) {
    int j = blockIdx.x * 256 + threadIdx.x;
    int c = blockIdx.y;
    if (j >= RDIM) return;
    unsigned n = 0;
    const float* p = W + (size_t)c * 500 * RDIM + j;
    for (int i = 0; i < 500; i++) n += (p[(size_t)i * RDIM] != 0.0f);
    cnts[c * RDIM + j] = n;
}

// ---- compress pass 2: exclusive prefix over chunks; totals -> cnts[0..RDIM) ----
__global__ __launch_bounds__(256) void offs_k(unsigned* __restrict__ cnts,
                                              unsigned* __restrict__ offs) {
    int j = blockIdx.x * 256 + threadIdx.x;
    if (j >= RDIM) return;
    unsigned run = 0;
    for (int c = 0; c < CH; c++) {
        offs[c * RDIM + j] = run;
        run += cnts[c * RDIM + j];
    }
    cnts[j] = run;
}

// ---- compress pass 3: per-block slot-group loop bound ----
__global__ __launch_bounds__(256) void kmax_k(const unsigned* __restrict__ totals,
                                              int* __restrict__ kmax) {
    int b = blockIdx.x * 256 + threadIdx.x;
    if (b >= NBLK) return;
    unsigned m = 0;
    for (int jl = 0; jl < CB; jl++) {
        unsigned t = totals[b * CB + jl];
        m = t > m ? t : m;
    }
    m = (m + 3) >> 2;                              // slot groups of 4
    kmax[b] = (int)(m < (CAP / 4) ? m : (CAP / 4));
}

// ---- compress pass 4: fill packed [b][sg][col][4]; pads pre-zeroed by memset ----
__global__ __launch_bounds__(256) void fill_k(const float* __restrict__ W,
                                              const unsigned* __restrict__ offs,
                                              unsigned* __restrict__ P) {
    int j = blockIdx.x * 256 + threadIdx.x;
    int c = blockIdx.y;
    if (j >= RDIM) return;
    unsigned slot = offs[c * RDIM + j];
    unsigned base = (unsigned)(j >> 4) * (CAP * CB) + (unsigned)(j & 15) * 4;
    int r0 = c * 500;
    for (int i = 0; i < 500; i++) {
        float w = W[(size_t)(r0 + i) * RDIM + j];
        if (w != 0.0f) {
            if (slot < CAP)
                P[base + (slot >> 2) * (CB * 4) + (slot & 3)] =
                    pack_rne(w, (unsigned)(r0 + i));
            slot++;
        }
    }
}

// ---- MFMA GEMM: C_f32[M,N] = A[M,K] @ B_f32[K,N] (A fp32 or bf16, staged bf16) ----
#define BM 64
#define BN 64
#define BK 32
#define LDP 56

__device__ inline bf16x8 load8(const float* p) {
    const f32x4* q = (const f32x4*)p;
    f32x4 f0 = q[0], f1 = q[1];
    bf16x8 r;
    r[0] = (bf16)f0[0]; r[1] = (bf16)f0[1]; r[2] = (bf16)f0[2]; r[3] = (bf16)f0[3];
    r[4] = (bf16)f1[0]; r[5] = (bf16)f1[1]; r[6] = (bf16)f1[2]; r[7] = (bf16)f1[3];
    return r;
}
__device__ inline bf16x8 load8(const bf16* p) { return *(const bf16x8*)p; }

template <typename AT>
__global__ __launch_bounds__(256) void gemm_k(const AT* __restrict__ A,
                                              const float* __restrict__ B,
                                              float* __restrict__ C,
                                              int M, int N, int K,
                                              int lda, int ldb, int ldc) {
    __shared__ bf16 As[BM][LDP];
    __shared__ bf16 Bs[BN][LDP];
    int tid  = threadIdx.x;
    int wave = tid >> 6, lane = tid & 63;
    int q    = lane >> 4;
    int l16  = lane & 15;
    int m0 = blockIdx.y * BM;
    int n0 = blockIdx.x * BN;

    int arow = tid >> 2;
    int acol = (tid & 3) * 8;
    int brow = tid >> 3;
    int bcol = (tid & 7) * 8;

    f32x4 acc[4];
    for (int nb = 0; nb < 4; nb++) for (int r = 0; r < 4; r++) acc[nb][r] = 0.f;

    for (int k0 = 0; k0 < K; k0 += BK) {
        bf16x8 av; for (int e = 0; e < 8; e++) av[e] = (bf16)0.f;
        if (m0 + arow < M)
            av = load8(A + (size_t)(m0 + arow) * lda + k0 + acol);
        bf16x8 bv;
        if (n0 + bcol + 8 <= N)
            bv = load8(B + (size_t)(k0 + brow) * ldb + n0 + bcol);
        else {
            for (int e = 0; e < 8; e++) {
                int col = n0 + bcol + e;
                bv[e] = (col < N) ? (bf16)B[(size_t)(k0 + brow) * ldb + col] : (bf16)0.f;
            }
        }
        __syncthreads();
        *(bf16x8*)&As[arow][acol] = av;
        for (int e = 0; e < 8; e++) Bs[bcol + e][brow] = bv[e];
        __syncthreads();

        bf16x8 af = *(const bf16x8*)&As[wave * 16 + l16][q * 8];
        #pragma unroll
        for (int nb = 0; nb < 4; nb++) {
            bf16x8 bfr = *(const bf16x8*)&Bs[nb * 16 + l16][q * 8];
            acc[nb] = __builtin_amdgcn_mfma_f32_16x16x32_bf16(af, bfr, acc[nb], 0, 0, 0);
        }
    }
    for (int nb = 0; nb < 4; nb++)
        for (int r = 0; r < 4; r++) {
            int row = m0 + wave * 16 + q * 4 + r;   // C/D: col=lane&15, row=q*4+r [m89]
            int col = n0 + nb * 16 + l16;
            if (row < M && col < N) C[(size_t)row * ldc + col] = acc[nb][r];
        }
}

// ---- persistent scan, custom lockstep barrier, asm bypass staging ----
// 250 blocks x 512 thr; block b owns cols [16b,16b+16); jl=tid&15, ks=tid>>4.
__global__ __launch_bounds__(512, 2) void scan_coop(
        const unsigned* __restrict__ P, const int* __restrict__ kmax,
        const float* __restrict__ U, float* __restrict__ va, float* __restrict__ vb,
        float* __restrict__ outbase, bf16* __restrict__ vhist,
        unsigned* __restrict__ cnt) {
    __shared__ __align__(16) float vsh[RDIM];
    __shared__ float red[8 * CB];
    int tid = threadIdx.x, b = blockIdx.x;
    int jl = tid & (CB - 1), ks = tid >> 4;          // ks 0..31
    const unsigned* Pb = P + (size_t)b * (CAP * CB);
    int kg = kmax[b];

    for (int t = 0; t < TSTEPS; t++) {
        const float* vo = (t & 1) ? vb : va;
        float*       vn = (t & 1) ? va : vb;

        if (t > 0) {                    // wait: all blocks finished step t-1
            if (tid == 0) {
                unsigned target = (unsigned)NBLK * (unsigned)t;
                for (;;) {
                    unsigned s = 0;
                    #pragma unroll
                    for (int i = 0; i < 8; i++)
                        s += __hip_atomic_load(cnt + i * 16, __ATOMIC_RELAXED,
                                               __HIP_MEMORY_SCOPE_AGENT);
                    if (s >= target) break;
                    __builtin_amdgcn_s_sleep(1);
                }
            }
            __syncthreads();            // holds waves 1..7 until step t data ready
        }

        float uval = 0.f;               // prefetch U early
        if (tid < CB) uval = U[(size_t)t * RDIM + b * CB + tid];

        // staging: 2 x 16B bypass loads in flight, 1 drain  (1000 dwordx4 chunks)
        {
            const f32x4* vo4 = (const f32x4*)vo;
            int c1 = tid + 512; if (c1 > 999) c1 = 999;
            f32x4 ra, rb;
            stage2((const float*)(vo4 + tid), (const float*)(vo4 + c1), ra, rb);
            ((f32x4*)vsh)[tid] = ra;
            if (tid < 488) ((f32x4*)vsh)[tid + 512] = rb;
        }
        __syncthreads();

        float acc = 0.f;
        for (int sg = ks; sg < kg; sg += 32) {
            uint4v p = *(const uint4v*)(Pb + sg * (CB * 4) + jl * 4);  // L2-hot
            #pragma unroll
            for (int e = 0; e < 4; e++) {
                unsigned pe = p[e];
                acc += vsh[pe & 0xFFFFu] * __uint_as_float(pe & 0xFFFF0000u);
            }
        }
        // reduce ks within wave (4 ks values/wave share jl)
        acc += __shfl_xor(acc, 16, 64);
        acc += __shfl_xor(acc, 32, 64);
        int lane = tid & 63;
        if (lane < CB) red[(tid >> 6) * CB + lane] = acc;
        __syncthreads();

        float vnj = 0.f;
        int j = b * CB + (tid & (CB - 1));
        if (tid < CB) {
            float s = 0.f;
            #pragma unroll
            for (int c = 0; c < 8; c++) s += red[c * CB + tid];
            float z = s + uval;
            float e2 = __expf(2.0f * z);                  // tanh = 1 - 2/(e^2z+1)
            vnj = 0.5f * vsh[j] + 0.5f * (1.0f - 2.0f / (e2 + 1.0f));
            __hip_atomic_store(vn + j, vnj, __ATOMIC_RELAXED,
                               __HIP_MEMORY_SCOPE_AGENT);  // to L3
        }
        // wave 0 only path matters: drain vn stores, then signal arrival;
        // out/vhist writes go AFTER the signal (drain during next poll).
        asm volatile("s_waitcnt vmcnt(0)" ::: "memory");
        if (tid == 0)
            __hip_atomic_fetch_add(cnt + (b & 7) * 16, 1u, __ATOMIC_RELAXED,
                                   __HIP_MEMORY_SCOPE_AGENT);
        if (tid < CB) {
            outbase[(size_t)t * 8000 + j] = vnj;
            if (vhist) vhist[(size_t)t * RDIM + j] = (bf16)vnj;
        }
    }
}

// ---- launch ----
extern "C" void kernel_launch(void* const* d_in, const int* in_sizes, int n_in,
                              void* d_out, int out_size, void* d_ws, size_t ws_size,
                              hipStream_t stream) {
    const float* x    = (const float*)d_in[0];   // [1000][4096]
    const float* Win1 = (const float*)d_in[1];   // [4096][4000]
    const float* W1   = (const float*)d_in[2];   // [4000][4000]
    const float* Win2 = (const float*)d_in[3];   // [4000][4000]
    const float* W2   = (const float*)d_in[4];   // [4000][4000]
    float* out = (float*)d_out;                  // [1000][8000]

    char* ws = (char*)d_ws;
    float*    U     = (float*)(ws);
    unsigned* cnts  = (unsigned*)(ws);                 // [8][4000], dead after compress
    unsigned* offs  = (unsigned*)(ws + 128000);        // [8][4000], dead after compress
    unsigned* P1    = (unsigned*)(ws + 16000000);
    unsigned* P2    = (unsigned*)(ws + 26240000);
    bf16*     V1bf  = (bf16*)(ws + 36480000);          // [1000][4000]
    int*      kmax1 = (int*)(ws + 44480000);
    int*      kmax2 = (int*)(ws + 44482000);
    float*    vbuf  = (float*)(ws + 44484000);         // [4][4000]
    unsigned* cnt1  = (unsigned*)(ws + 44548096);      // 8 counters, 64B stride
    unsigned* cnt2  = (unsigned*)(ws + 44548608);

    hipMemsetAsync(vbuf, 0, 4 * RDIM * sizeof(float), stream);
    hipMemsetAsync(cnt1, 0, 1024, stream);             // covers cnt1+cnt2
    hipMemsetAsync(P1, 0, (size_t)NBLK * CAP * CB * 4, stream);
    hipMemsetAsync(P2, 0, (size_t)NBLK * CAP * CB * 4, stream);

    dim3 cg16(16, CH);
    count_k<<<cg16, 256, 0, stream>>>(W1, cnts);
    offs_k<<<16, 256, 0, stream>>>(cnts, offs);
    kmax_k<<<1, 256, 0, stream>>>(cnts, kmax1);
    fill_k<<<cg16, 256, 0, stream>>>(W1, offs, P1);
    count_k<<<cg16, 256, 0, stream>>>(W2, cnts);
    offs_k<<<16, 256, 0, stream>>>(cnts, offs);
    kmax_k<<<1, 256, 0, stream>>>(cnts, kmax2);
    fill_k<<<cg16, 256, 0, stream>>>(W2, offs, P2);

    dim3 gg((RDIM + BN - 1) / BN, (TSTEPS + BM - 1) / BM);
    gemm_k<float><<<gg, 256, 0, stream>>>(x, Win1, U, TSTEPS, RDIM, 4096,
                                          4096, RDIM, RDIM);

    {   // scan layer 1
        const unsigned* Pp = P1; const int* km = kmax1; const float* Up = U;
        float* va = vbuf; float* vb = vbuf + RDIM;
        float* ob = out; bf16* vh = V1bf; unsigned* cn = cnt1;
        void* args[] = {&Pp, &km, &Up, &va, &vb, &ob, &vh, &cn};
        hipLaunchCooperativeKernel((void*)scan_coop, dim3(NBLK), dim3(512),
                                   args, 0, stream);
    }

    gemm_k<bf16><<<gg, 256, 0, stream>>>(V1bf, Win2, U, TSTEPS, RDIM, RDIM,
                                         RDIM, RDIM, RDIM);

    {   // scan layer 2
        const unsigned* Pp = P2; const int* km = kmax2; const float* Up = U;
        float* va = vbuf + 2 * RDIM; float* vb = vbuf + 3 * RDIM;
        float* ob = out + RDIM; bf16* vh = nullptr; unsigned* cn = cnt2;
        void* args[] = {&Pp, &km, &Up, &va, &vb, &ob, &vh, &cn};
        hipLaunchCooperativeKernel((void*)scan_coop, dim3(NBLK), dim3(512),
                                   args, 0, stream);
    }
}